// Round 5
// baseline (357.811 us; speedup 1.0000x reference)
//
#include <hip/hip_runtime.h>
#include <cstdint>

// ---------------------------------------------------------------------------
// ConvModule: LN -> GEMM(512->1024)+SiLU -> conv K=5 (1024->1024) -> GLU ->
//             BN -> GEMM(512->512).  B=16, T=1024, C=512. fp32 I/O, bf16 MFMA.
// Round 14: conv re-tiled 256M x 128N (4 waves, 2x2 of 128Mx64N wave tiles).
// WHY: R13 refuted the occupancy theory (3rd block gave +0%). Arithmetic
// says LDS-READ-BOUND: 64x64 waves need 40 ds_read_b128 per 80 MFMA ->
// LDS pipe ~7100 cyc/CU-chunk vs MFMA ~3100 (MfmaUtil 42% == 3100/7100).
// 128x64 wave tiles amortize B frags over 2x M: 60 reads per 160 MFMA
// (-25% reads/FLOP) -> LDS ~= MFMA ~= 6200 cyc, near-balanced.
// B side (frag-major XOR-swizzled LDS, BGLD/BSTF, n0 width 128) UNCHANGED.
// A side: 260 rows x stride-40, single-buffered, 5 relay regs. acc[8][4]
// = 128 AGPR; mi split in halves of 4 keeps live af[4]+bfr[4] -> arch
// ~112 + 128 acc = 240 <= 256 (2 waves/SIMD under (256,2)).
// Grid 64x8 = 512 blocks = exactly 2/CU. LDS 61.8 KB -> 2 blocks/CU.
// Lessons: indexed reg arrays spill (R5/R8); named scalars don't (R9);
// direct-global frags TCP-bound (R4/R6/R7); never force min-waves beyond
// (VGPR+AGPR) budget (R11); occupancy is NOT the conv limiter (R13).
// ---------------------------------------------------------------------------

#define NB    16
#define TT    1024
#define CC    512
#define C2    1024
#define TPAD  1028        // T + 4 pad rows (2 each side) per batch

typedef unsigned short u16;
typedef short bf16x8 __attribute__((ext_vector_type(8)));
typedef float f32x4  __attribute__((ext_vector_type(4)));

__device__ __forceinline__ float bf2f(u16 u) {
  union { unsigned int i; float f; } v; v.i = ((unsigned int)u) << 16; return v.f;
}
__device__ __forceinline__ u16 f2bf(float f) {
  union { float f; unsigned int i; } v; v.f = f;
  unsigned int x = v.i;
  return (u16)((x + 0x7fffu + ((x >> 16) & 1u)) >> 16);  // RNE
}

// ---------------------------------------------------------------------------
__global__ __launch_bounds__(256) void prep_k(
    const float* __restrict__ w1, u16* __restrict__ w1b,
    const float* __restrict__ w3, u16* __restrict__ w3b,
    u16* __restrict__ h1p) {
  const int b = blockIdx.x;
  if (b < 512) {
    const int i = (b * 256 + threadIdx.x) * 4;
    float4 v = *(const float4*)(w1 + i);
    u16 o[4] = { f2bf(v.x), f2bf(v.y), f2bf(v.z), f2bf(v.w) };
    *(uint2*)(w1b + i) = *(const uint2*)o;
  } else if (b < 768) {
    const int i = ((b - 512) * 256 + threadIdx.x) * 4;
    float4 v = *(const float4*)(w3 + i);
    u16 o[4] = { f2bf(v.x), f2bf(v.y), f2bf(v.z), f2bf(v.w) };
    *(uint2*)(w3b + i) = *(const uint2*)o;
  } else {
    const int idx = (b - 768) * 256 + threadIdx.x;
    const int bb  = idx >> 9;
    const int rem = idx & 511;
    const int ri  = rem >> 7;
    const int c8  = (rem & 127) * 8;
    const int row = bb * TPAD + (ri < 2 ? ri : 1024 + ri);   // 0,1,1026,1027
    uint4 z = make_uint4(0u, 0u, 0u, 0u);
    *(uint4*)(h1p + (size_t)row * C2 + c8) = z;
  }
}

// ---------------------------------------------------------------------------
// w2 fp32 (K, I, O) -> w2t bf16 (K, O, I)
__global__ void transpose_w2(const float* __restrict__ w2, u16* __restrict__ w2t) {
  __shared__ u16 t[64][65];
  const int k  = blockIdx.z;
  const int i0 = blockIdx.x * 64, o0 = blockIdx.y * 64;
  const int tx = threadIdx.x, ty = threadIdx.y;
  for (int r = ty; r < 64; r += 4)
    t[r][tx] = f2bf(w2[((size_t)(k * C2) + i0 + r) * C2 + o0 + tx]);
  __syncthreads();
  for (int r = ty; r < 64; r += 4)
    w2t[((size_t)(k * C2) + o0 + r) * C2 + i0 + tx] = t[tx][r];
}

// ---------------------------------------------------------------------------
__global__ __launch_bounds__(256) void layernorm_k(
    const float* __restrict__ x, const float* __restrict__ lng,
    const float* __restrict__ lnb, u16* __restrict__ out) {
  const int tok  = blockIdx.x * 4 + (threadIdx.x >> 6);
  const int lane = threadIdx.x & 63;
  const float* xp = x + (size_t)tok * CC + lane * 8;
  float f[8];
  *(float4*)(f)     = *(const float4*)(xp);
  *(float4*)(f + 4) = *(const float4*)(xp + 4);
  float s = 0.f, s2 = 0.f;
#pragma unroll
  for (int j = 0; j < 8; j++) { s += f[j]; s2 += f[j] * f[j]; }
#pragma unroll
  for (int m = 32; m >= 1; m >>= 1) { s += __shfl_xor(s, m, 64); s2 += __shfl_xor(s2, m, 64); }
  const float mu  = s  * (1.f / 512.f);
  const float var = s2 * (1.f / 512.f) - mu * mu;
  const float rs  = rsqrtf(var + 1e-5f);
  u16 ov[8];
#pragma unroll
  for (int j = 0; j < 8; j++) {
    const int c = lane * 8 + j;
    ov[j] = f2bf((f[j] - mu) * rs * lng[c] + lnb[c]);
  }
  *(uint4*)(out + (size_t)tok * CC + lane * 8) = *(const uint4*)ov;
}

// ---------------------------------------------------------------------------
// GEMM out[m,n] = sum_k A[m,k]*Bt[n,k] + bias[n].  128x128 tile, BK=32.
// (R8/R9 version — proven, kept.)
template <int EPI>
__global__ __launch_bounds__(256, 3) void gemm_bt(
    const u16* __restrict__ A, const u16* __restrict__ Bt,
    const float* __restrict__ bias, void* __restrict__ outv,
    const int Kd, const int ldA) {
  __shared__ __align__(16) u16 smem[20480];   // lsA 2x5120 | lsB 2x5120
  const int tid  = threadIdx.x;
  const int m0   = blockIdx.x * 128;
  const int n0   = blockIdx.y * 128;
  const int wave = tid >> 6, lane = tid & 63;
  const int wm = (wave & 1) * 64, wn = (wave >> 1) * 64;
  const int quad = lane >> 4, l16 = lane & 15;
  const int row = tid >> 2;            // 0..63
  const int kc  = (tid & 3) * 8;       // 0/8/16/24
  const int J = Kd >> 5;               // 16

  const u16* Ap0 = A + (size_t)(m0 + row) * ldA + kc;
  const u16* Ap1 = Ap0 + (size_t)64 * ldA;
  const u16* Bp0 = Bt + (size_t)(n0 + row) * Kd + kc;
  const u16* Bp1 = Bp0 + (size_t)64 * Kd;

  f32x4 acc[4][4] = {};
  uint4 rA0 = *(const uint4*)Ap0, rA1 = *(const uint4*)Ap1;
  uint4 rB0 = *(const uint4*)Bp0, rB1 = *(const uint4*)Bp1;
  *(uint4*)(smem + row * 40 + kc)                = rA0;
  *(uint4*)(smem + (64 + row) * 40 + kc)         = rA1;
  *(uint4*)(smem + 10240 + row * 40 + kc)        = rB0;
  *(uint4*)(smem + 10240 + (64 + row) * 40 + kc) = rB1;
  rA0 = *(const uint4*)(Ap0 + 32); rA1 = *(const uint4*)(Ap1 + 32);
  rB0 = *(const uint4*)(Bp0 + 32); rB1 = *(const uint4*)(Bp1 + 32);
  __syncthreads();

#pragma unroll 1
  for (int j = 0; j < J; j++) {
    const u16* curA = smem + (j & 1) * 5120;
    const u16* curB = smem + 10240 + (j & 1) * 5120;
    if (j + 1 < J) {
      u16* nxtA = smem + ((j + 1) & 1) * 5120;
      u16* nxtB = smem + 10240 + ((j + 1) & 1) * 5120;
      *(uint4*)(nxtA + row * 40 + kc)        = rA0;
      *(uint4*)(nxtA + (64 + row) * 40 + kc) = rA1;
      *(uint4*)(nxtB + row * 40 + kc)        = rB0;
      *(uint4*)(nxtB + (64 + row) * 40 + kc) = rB1;
    }
    {
      const int k2 = (j + 2 < J) ? (j + 2) * 32 : 0;
      rA0 = *(const uint4*)(Ap0 + k2); rA1 = *(const uint4*)(Ap1 + k2);
      rB0 = *(const uint4*)(Bp0 + k2); rB1 = *(const uint4*)(Bp1 + k2);
    }
    bf16x8 af[4], bfr[4];
#pragma unroll
    for (int i = 0; i < 4; i++)
      af[i] = *(const bf16x8*)(curA + (wm + i * 16 + l16) * 40 + quad * 8);
#pragma unroll
    for (int i = 0; i < 4; i++)
      bfr[i] = *(const bf16x8*)(curB + (wn + i * 16 + l16) * 40 + quad * 8);
#pragma unroll
    for (int mi = 0; mi < 4; mi++)
#pragma unroll
      for (int ni = 0; ni < 4; ni++)
        acc[mi][ni] = __builtin_amdgcn_mfma_f32_16x16x32_bf16(
            af[mi], bfr[ni], acc[mi][ni], 0, 0, 0);
    __syncthreads();
  }

  float bv[4];
#pragma unroll
  for (int ni = 0; ni < 4; ni++) bv[ni] = bias[n0 + wn + ni * 16 + l16];

  if (EPI == 0) {
    u16* epi = smem + wave * 4608;       // 64 x 72 u16, private
#pragma unroll
    for (int mi = 0; mi < 4; mi++)
#pragma unroll
      for (int ni = 0; ni < 4; ni++)
#pragma unroll
        for (int r = 0; r < 4; r++) {
          float v = acc[mi][ni][r] + bv[ni];
          v = v / (1.f + __expf(-v));    // SiLU
          epi[(mi * 16 + quad * 4 + r) * 72 + ni * 16 + l16] = f2bf(v);
        }
    u16* h1p = (u16*)outv;
#pragma unroll
    for (int p = 0; p < 8; p++) {
      const int rrow = p * 8 + (lane >> 3);
      const int colb = (lane & 7) * 8;
      uint4 v = *(const uint4*)(epi + rrow * 72 + colb);
      const int rr = m0 + wm + rrow;
      const int bb = rr >> 10, tt = rr & 1023;
      *(uint4*)(h1p + (size_t)(bb * TPAD + tt + 2) * C2 + n0 + wn + colb) = v;
    }
  } else {
    float* fepi = (float*)(smem + wave * 4608);   // 2 x (16 x 68) f32
    float* outf = (float*)outv;
#pragma unroll
    for (int mi = 0; mi < 4; mi++) {
      float* fp = fepi + (mi & 1) * 1088;
#pragma unroll
      for (int ni = 0; ni < 4; ni++)
#pragma unroll
        for (int r = 0; r < 4; r++)
          fp[(quad * 4 + r) * 68 + ni * 16 + l16] = acc[mi][ni][r] + bv[ni];
#pragma unroll
      for (int p = 0; p < 4; p++) {
        const int rrow = p * 4 + (lane >> 4);
        const int col  = (lane & 15) * 4;
        float4 v = *(const float4*)(fp + rrow * 68 + col);
        *(float4*)(outf + (size_t)(m0 + wm + mi * 16 + rrow) * CC + n0 + wn + col) = v;
      }
    }
  }
}

// ---------------------------------------------------------------------------
// 5-tap conv: 256M x 128N block, 4 waves in 2x2 of 128M x 64N wave tiles.
// A: row-major stride-40, SINGLE-buffered rows 0..259 (taps read +k shift),
//    stored at chunk top; 5 relay regs (rA0-4, rA4 tid<16 for halo rows).
// B: FRAG-MAJOR single-buffered, XOR-SWIZZLED — IDENTICAL to R12/R13
//    (tap t frag-tile g at lsB + t*4096 + g*512; ix^((ix>>3)&7) involution;
//    write+read conflict-free). 128-wide N panel unchanged.
// 2 barriers/chunk; A+B relay 1-chunk distance (chunk ~6200 cyc >> HBM 900).
// 61.8 KB LDS -> 2 blocks/CU.  acc[8][4]=128 AGPR; mi processed in halves
// of 4 so live frags stay af[4]+bfr[4]; arch ~112 + 128 = ~240 <= 256.
__global__ __launch_bounds__(256, 2) void conv5_mfma(
    const u16* __restrict__ h1p, const u16* __restrict__ w2t,
    const float* __restrict__ b2, u16* __restrict__ out) {
  __shared__ __align__(16) u16 smem[30880];  // lsA 10400 | lsB 20480 @10400
  const int tid = threadIdx.x;
  const int mt  = blockIdx.x;                // m-tile 0..63 (256 rows each)
  const int n0  = blockIdx.y * 128;          // n-tile 0..7
  const int bb  = mt >> 2;
  const int t0  = (mt & 3) * 256;
  const size_t arow0 = (size_t)bb * TPAD + t0;
  const int wave = tid >> 6, lane = tid & 63;
  const int wm = (wave & 1) * 128, wn = (wave >> 1) * 64;
  const int quad = lane >> 4, l16 = lane & 15;
  const int row = tid >> 2;            // 0..63
  const int kc  = (tid & 3) * 8;       // 0/8/16/24
  const int slb = (lane ^ ((lane >> 3) & 7)) * 8;   // swizzled B read slot
  u16* lsB = smem + 10400;

  const u16* Ap0 = h1p + (arow0 + row) * C2 + kc;
  const u16* Ap1 = Ap0 + (size_t)64 * C2;
  const u16* Ap2 = Ap0 + (size_t)128 * C2;
  const u16* Ap3 = Ap0 + (size_t)192 * C2;
  const u16* Ap4 = h1p + (arow0 + 256 + row) * C2 + kc;   // tid<16: rows 256..259

  f32x4 acc[8][4] = {};
  uint4 rA0, rA1, rA2, rA3, rA4;
  uint4 rB0, rB1, rB2, rB3, rB4, rB5, rB6, rB7, rB8, rB9;

  // B relay: slot Q covers tap Q>>1, u = (Q&1)*256+tid -> n = n0+(u>>2),
  // k-range (u&3)*8..+8 at chunk offset I0.  LDS slot index XOR-swizzled.
#define BGLD(R, Q, I0) { const int u = ((Q) & 1) * 256 + tid;                  \
    R = *(const uint4*)(w2t + (size_t)(((Q) >> 1) * C2 + n0 + (u >> 2)) * C2   \
                        + (I0) + (u & 3) * 8); }
#define BSTF(R, Q) { const int u = ((Q) & 1) * 256 + tid; const int nn = u >> 2; \
    const int ix = (u & 3) * 16 + (nn & 15);                                    \
    *(uint4*)(lsB + ((Q) >> 1) * 4096 + (nn >> 4) * 512                         \
              + (ix ^ ((ix >> 3) & 7)) * 8) = R; }
#define BGLD_ALL(I0) BGLD(rB0,0,I0) BGLD(rB1,1,I0) BGLD(rB2,2,I0) \
    BGLD(rB3,3,I0) BGLD(rB4,4,I0) BGLD(rB5,5,I0) BGLD(rB6,6,I0)   \
    BGLD(rB7,7,I0) BGLD(rB8,8,I0) BGLD(rB9,9,I0)
#define BSTF_ALL() BSTF(rB0,0) BSTF(rB1,1) BSTF(rB2,2) BSTF(rB3,3) \
    BSTF(rB4,4) BSTF(rB5,5) BSTF(rB6,6) BSTF(rB7,7) BSTF(rB8,8) BSTF(rB9,9)

  // prologue: A(0), B(0) -> regs only (stored at top of chunk 0)
  rA0 = *(const uint4*)Ap0; rA1 = *(const uint4*)Ap1;
  rA2 = *(const uint4*)Ap2; rA3 = *(const uint4*)Ap3;
  if (tid < 16) rA4 = *(const uint4*)Ap4;
  BGLD_ALL(0)

#pragma unroll 1
  for (int j = 0; j < 32; j++) {
    __syncthreads();                       // chunk j-1 LDS reads complete
    *(uint4*)(smem + row * 40 + kc)         = rA0;   // lsA = A(j)
    *(uint4*)(smem + (64 + row) * 40 + kc)  = rA1;
    *(uint4*)(smem + (128 + row) * 40 + kc) = rA2;
    *(uint4*)(smem + (192 + row) * 40 + kc) = rA3;
    if (tid < 16) *(uint4*)(smem + (256 + row) * 40 + kc) = rA4;
    BSTF_ALL()                             // lsB = B(j)
    __syncthreads();                       // staging visible
    {                                      // relay loads: A(j+1), B(j+1)
      const int ib = (j + 1 < 32) ? (j + 1) * 32 : 0;
      BGLD_ALL(ib)
      rA0 = *(const uint4*)(Ap0 + ib);
      rA1 = *(const uint4*)(Ap1 + ib);
      rA2 = *(const uint4*)(Ap2 + ib);
      rA3 = *(const uint4*)(Ap3 + ib);
      if (tid < 16) rA4 = *(const uint4*)(Ap4 + ib);
    }
#pragma unroll
    for (int k = 0; k < 5; k++) {
      bf16x8 bfr[4];
#pragma unroll
      for (int i = 0; i < 4; i++)
        bfr[i] = *(const bf16x8*)(lsB + k * 4096 + ((wn >> 4) + i) * 512 + slb);
#pragma unroll
      for (int h = 0; h < 2; h++) {
        bf16x8 af[4];
#pragma unroll
        for (int i = 0; i < 4; i++)
          af[i] = *(const bf16x8*)(smem + (wm + (h * 4 + i) * 16 + l16 + k) * 40 + quad * 8);
#pragma unroll
        for (int mi = 0; mi < 4; mi++)
#pragma unroll
          for (int ni = 0; ni < 4; ni++)
            acc[h * 4 + mi][ni] = __builtin_amdgcn_mfma_f32_16x16x32_bf16(
                af[mi], bfr[ni], acc[h * 4 + mi][ni], 0, 0, 0);
      }
    }
  }
#undef BGLD
#undef BSTF
#undef BGLD_ALL
#undef BSTF_ALL
  __syncthreads();

  float bv[4];
#pragma unroll
  for (int ni = 0; ni < 4; ni++) bv[ni] = b2[n0 + wn + ni * 16 + l16];

  u16* epi = smem + wave * 4608;         // 64 x 72 u16, private per wave
  const size_t orow0 = (size_t)bb * TT + t0;
#pragma unroll
  for (int h = 0; h < 2; h++) {
#pragma unroll
    for (int mi = 0; mi < 4; mi++)
#pragma unroll
      for (int ni = 0; ni < 4; ni++)
#pragma unroll
        for (int r = 0; r < 4; r++)
          epi[(mi * 16 + quad * 4 + r) * 72 + ni * 16 + l16] =
              f2bf(acc[h * 4 + mi][ni][r] + bv[ni]);
#pragma unroll
    for (int p = 0; p < 8; p++) {
      const int rrow = p * 8 + (lane >> 3);
      const int colb = (lane & 7) * 8;
      uint4 v = *(const uint4*)(epi + rrow * 72 + colb);
      *(uint4*)(out + (orow0 + wm + h * 64 + rrow) * C2 + n0 + wn + colb) = v;
    }
  }
}

// ---------------------------------------------------------------------------
__global__ __launch_bounds__(256) void glu_bn_k(
    const u16* __restrict__ hc, const float* __restrict__ bg,
    const float* __restrict__ bb_, const float* __restrict__ bm,
    const float* __restrict__ bv, u16* __restrict__ out) {
  const int idx = blockIdx.x * 256 + threadIdx.x;
  const int r  = idx >> 6;
  const int c8 = (idx & 63) * 8;
  const u16* pa = hc + (size_t)r * C2 + c8;
  uint4 ra = *(const uint4*)pa;
  uint4 rg = *(const uint4*)(pa + CC);
  u16 av[8], gv[8], ov[8];
  *(uint4*)av = ra; *(uint4*)gv = rg;
#pragma unroll
  for (int j = 0; j < 8; j++) {
    const int c = c8 + j;
    const float a = bf2f(av[j]);
    const float g = bf2f(gv[j]);
    const float h = a / (1.f + __expf(-g));
    const float sc = bg[c] * rsqrtf(bv[c] + 1e-5f);
    ov[j] = f2bf((h - bm[c]) * sc + bb_[c]);
  }
  *(uint4*)(out + (size_t)r * CC + c8) = *(const uint4*)ov;
}

// ---------------------------------------------------------------------------
extern "C" void kernel_launch(void* const* d_in, const int* in_sizes, int n_in,
                              void* d_out, int out_size, void* d_ws, size_t ws_size,
                              hipStream_t stream) {
  const float* x   = (const float*)d_in[0];
  const float* lng = (const float*)d_in[1];
  const float* lnb = (const float*)d_in[2];
  const float* w1  = (const float*)d_in[3];
  const float* b1  = (const float*)d_in[4];
  const float* w2  = (const float*)d_in[5];
  const float* b2  = (const float*)d_in[6];
  const float* bng = (const float*)d_in[7];
  const float* bnb = (const float*)d_in[8];
  const float* bnm = (const float*)d_in[9];
  const float* bnv = (const float*)d_in[10];
  const float* w3  = (const float*)d_in[11];
  const float* b3  = (const float*)d_in[12];

  u16* ws  = (u16*)d_ws;
  u16* hln = ws;                               // 16384*512
  u16* h2  = hln;                              // alias (hln dead after GEMM1)
  u16* h1p = ws + 8388608;                     // 16*1028*1024
  u16* w2t = h1p + 16842752;                   // 5*1024*1024
  u16* hcv = w2t + 5242880;                    // 16384*1024
  u16* w1b = hcv + 16777216;                   // 1024*512
  u16* w3b = w1b + 524288;                     // 512*512

  prep_k      <<<800, 256, 0, stream>>>(w1, w1b, w3, w3b, h1p);
  transpose_w2<<<dim3(16, 16, 5), dim3(64, 4), 0, stream>>>(w2, w2t);
  layernorm_k <<<4096, 256, 0, stream>>>(x, lng, lnb, hln);
  gemm_bt<0>  <<<dim3(128, 8), 256, 0, stream>>>(hln, w1b, b1, h1p, 512, 512);
  conv5_mfma  <<<dim3(64, 8), 256, 0, stream>>>(h1p, w2t, b2, hcv);
  glu_bn_k    <<<4096, 256, 0, stream>>>(hcv, bng, bnb, bnm, bnv, h2);
  gemm_bt<1>  <<<dim3(128, 4), 256, 0, stream>>>(h2, w3b, b3, d_out, 512, 512);
}

// Round 6
// 321.203 us; speedup vs baseline: 1.1140x; 1.1140x over previous
//
#include <hip/hip_runtime.h>
#include <cstdint>

// ---------------------------------------------------------------------------
// ConvModule: LN -> GEMM(512->1024)+SiLU -> conv K=5 (1024->1024) -> GLU ->
//             BN -> GEMM(512->512).  B=16, T=1024, C=512. fp32 I/O, bf16 MFMA.
// Round 15: R14's 256Mx128N tile (128x64 wave tiles, -25% LDS reads/FLOP)
// with B staged via global_load_lds DIRECT (per-lane global addr, linear
// LDS dest): kills rB0-9 relay (40 VGPRs) + BSTF ds_writes + XOR swizzle
// (write was the only conflicted side; linear read was already clean).
// Arch ~90 + 128 AGPR ~= 218 <= 256 -> no spills (R14 spilled at 256).
// B is L2-hot (1.25MB/n0-col shared by 64 blocks) -> ~200cy exposure at
// barrier2, covered by A ds_writes issued in between.
// A side unchanged from R14: stride-40 rows 0..259, 5-reg relay, 1-chunk
// distance (R13 proved 1-chunk == 2-chunk at 184us).
// Lessons: indexed reg arrays spill (R5/R8); named scalars don't (R9);
// direct-global frags TCP-bound (R4/R6/R7); never exceed (VGPR+AGPR)=256
// at 2-wave (R14); occupancy not the conv limiter (R13).
// ---------------------------------------------------------------------------

#define NB    16
#define TT    1024
#define CC    512
#define C2    1024
#define TPAD  1028        // T + 4 pad rows (2 each side) per batch

typedef unsigned short u16;
typedef short bf16x8 __attribute__((ext_vector_type(8)));
typedef float f32x4  __attribute__((ext_vector_type(4)));
typedef __attribute__((address_space(3))) u16 lds_u16;
typedef const __attribute__((address_space(1))) u16 glb_u16;

__device__ __forceinline__ float bf2f(u16 u) {
  union { unsigned int i; float f; } v; v.i = ((unsigned int)u) << 16; return v.f;
}
__device__ __forceinline__ u16 f2bf(float f) {
  union { float f; unsigned int i; } v; v.f = f;
  unsigned int x = v.i;
  return (u16)((x + 0x7fffu + ((x >> 16) & 1u)) >> 16);  // RNE
}

// ---------------------------------------------------------------------------
__global__ __launch_bounds__(256) void prep_k(
    const float* __restrict__ w1, u16* __restrict__ w1b,
    const float* __restrict__ w3, u16* __restrict__ w3b,
    u16* __restrict__ h1p) {
  const int b = blockIdx.x;
  if (b < 512) {
    const int i = (b * 256 + threadIdx.x) * 4;
    float4 v = *(const float4*)(w1 + i);
    u16 o[4] = { f2bf(v.x), f2bf(v.y), f2bf(v.z), f2bf(v.w) };
    *(uint2*)(w1b + i) = *(const uint2*)o;
  } else if (b < 768) {
    const int i = ((b - 512) * 256 + threadIdx.x) * 4;
    float4 v = *(const float4*)(w3 + i);
    u16 o[4] = { f2bf(v.x), f2bf(v.y), f2bf(v.z), f2bf(v.w) };
    *(uint2*)(w3b + i) = *(const uint2*)o;
  } else {
    const int idx = (b - 768) * 256 + threadIdx.x;
    const int bb  = idx >> 9;
    const int rem = idx & 511;
    const int ri  = rem >> 7;
    const int c8  = (rem & 127) * 8;
    const int row = bb * TPAD + (ri < 2 ? ri : 1024 + ri);   // 0,1,1026,1027
    uint4 z = make_uint4(0u, 0u, 0u, 0u);
    *(uint4*)(h1p + (size_t)row * C2 + c8) = z;
  }
}

// ---------------------------------------------------------------------------
// w2 fp32 (K, I, O) -> w2t bf16 (K, O, I)
__global__ void transpose_w2(const float* __restrict__ w2, u16* __restrict__ w2t) {
  __shared__ u16 t[64][65];
  const int k  = blockIdx.z;
  const int i0 = blockIdx.x * 64, o0 = blockIdx.y * 64;
  const int tx = threadIdx.x, ty = threadIdx.y;
  for (int r = ty; r < 64; r += 4)
    t[r][tx] = f2bf(w2[((size_t)(k * C2) + i0 + r) * C2 + o0 + tx]);
  __syncthreads();
  for (int r = ty; r < 64; r += 4)
    w2t[((size_t)(k * C2) + o0 + r) * C2 + i0 + tx] = t[tx][r];
}

// ---------------------------------------------------------------------------
__global__ __launch_bounds__(256) void layernorm_k(
    const float* __restrict__ x, const float* __restrict__ lng,
    const float* __restrict__ lnb, u16* __restrict__ out) {
  const int tok  = blockIdx.x * 4 + (threadIdx.x >> 6);
  const int lane = threadIdx.x & 63;
  const float* xp = x + (size_t)tok * CC + lane * 8;
  float f[8];
  *(float4*)(f)     = *(const float4*)(xp);
  *(float4*)(f + 4) = *(const float4*)(xp + 4);
  float s = 0.f, s2 = 0.f;
#pragma unroll
  for (int j = 0; j < 8; j++) { s += f[j]; s2 += f[j] * f[j]; }
#pragma unroll
  for (int m = 32; m >= 1; m >>= 1) { s += __shfl_xor(s, m, 64); s2 += __shfl_xor(s2, m, 64); }
  const float mu  = s  * (1.f / 512.f);
  const float var = s2 * (1.f / 512.f) - mu * mu;
  const float rs  = rsqrtf(var + 1e-5f);
  u16 ov[8];
#pragma unroll
  for (int j = 0; j < 8; j++) {
    const int c = lane * 8 + j;
    ov[j] = f2bf((f[j] - mu) * rs * lng[c] + lnb[c]);
  }
  *(uint4*)(out + (size_t)tok * CC + lane * 8) = *(const uint4*)ov;
}

// ---------------------------------------------------------------------------
// GEMM out[m,n] = sum_k A[m,k]*Bt[n,k] + bias[n].  128x128 tile, BK=32.
// (R8/R9 version — proven, kept.)
template <int EPI>
__global__ __launch_bounds__(256, 3) void gemm_bt(
    const u16* __restrict__ A, const u16* __restrict__ Bt,
    const float* __restrict__ bias, void* __restrict__ outv,
    const int Kd, const int ldA) {
  __shared__ __align__(16) u16 smem[20480];   // lsA 2x5120 | lsB 2x5120
  const int tid  = threadIdx.x;
  const int m0   = blockIdx.x * 128;
  const int n0   = blockIdx.y * 128;
  const int wave = tid >> 6, lane = tid & 63;
  const int wm = (wave & 1) * 64, wn = (wave >> 1) * 64;
  const int quad = lane >> 4, l16 = lane & 15;
  const int row = tid >> 2;            // 0..63
  const int kc  = (tid & 3) * 8;       // 0/8/16/24
  const int J = Kd >> 5;               // 16

  const u16* Ap0 = A + (size_t)(m0 + row) * ldA + kc;
  const u16* Ap1 = Ap0 + (size_t)64 * ldA;
  const u16* Bp0 = Bt + (size_t)(n0 + row) * Kd + kc;
  const u16* Bp1 = Bp0 + (size_t)64 * Kd;

  f32x4 acc[4][4] = {};
  uint4 rA0 = *(const uint4*)Ap0, rA1 = *(const uint4*)Ap1;
  uint4 rB0 = *(const uint4*)Bp0, rB1 = *(const uint4*)Bp1;
  *(uint4*)(smem + row * 40 + kc)                = rA0;
  *(uint4*)(smem + (64 + row) * 40 + kc)         = rA1;
  *(uint4*)(smem + 10240 + row * 40 + kc)        = rB0;
  *(uint4*)(smem + 10240 + (64 + row) * 40 + kc) = rB1;
  rA0 = *(const uint4*)(Ap0 + 32); rA1 = *(const uint4*)(Ap1 + 32);
  rB0 = *(const uint4*)(Bp0 + 32); rB1 = *(const uint4*)(Bp1 + 32);
  __syncthreads();

#pragma unroll 1
  for (int j = 0; j < J; j++) {
    const u16* curA = smem + (j & 1) * 5120;
    const u16* curB = smem + 10240 + (j & 1) * 5120;
    if (j + 1 < J) {
      u16* nxtA = smem + ((j + 1) & 1) * 5120;
      u16* nxtB = smem + 10240 + ((j + 1) & 1) * 5120;
      *(uint4*)(nxtA + row * 40 + kc)        = rA0;
      *(uint4*)(nxtA + (64 + row) * 40 + kc) = rA1;
      *(uint4*)(nxtB + row * 40 + kc)        = rB0;
      *(uint4*)(nxtB + (64 + row) * 40 + kc) = rB1;
    }
    {
      const int k2 = (j + 2 < J) ? (j + 2) * 32 : 0;
      rA0 = *(const uint4*)(Ap0 + k2); rA1 = *(const uint4*)(Ap1 + k2);
      rB0 = *(const uint4*)(Bp0 + k2); rB1 = *(const uint4*)(Bp1 + k2);
    }
    bf16x8 af[4], bfr[4];
#pragma unroll
    for (int i = 0; i < 4; i++)
      af[i] = *(const bf16x8*)(curA + (wm + i * 16 + l16) * 40 + quad * 8);
#pragma unroll
    for (int i = 0; i < 4; i++)
      bfr[i] = *(const bf16x8*)(curB + (wn + i * 16 + l16) * 40 + quad * 8);
#pragma unroll
    for (int mi = 0; mi < 4; mi++)
#pragma unroll
      for (int ni = 0; ni < 4; ni++)
        acc[mi][ni] = __builtin_amdgcn_mfma_f32_16x16x32_bf16(
            af[mi], bfr[ni], acc[mi][ni], 0, 0, 0);
    __syncthreads();
  }

  float bv[4];
#pragma unroll
  for (int ni = 0; ni < 4; ni++) bv[ni] = bias[n0 + wn + ni * 16 + l16];

  if (EPI == 0) {
    u16* epi = smem + wave * 4608;       // 64 x 72 u16, private
#pragma unroll
    for (int mi = 0; mi < 4; mi++)
#pragma unroll
      for (int ni = 0; ni < 4; ni++)
#pragma unroll
        for (int r = 0; r < 4; r++) {
          float v = acc[mi][ni][r] + bv[ni];
          v = v / (1.f + __expf(-v));    // SiLU
          epi[(mi * 16 + quad * 4 + r) * 72 + ni * 16 + l16] = f2bf(v);
        }
    u16* h1p = (u16*)outv;
#pragma unroll
    for (int p = 0; p < 8; p++) {
      const int rrow = p * 8 + (lane >> 3);
      const int colb = (lane & 7) * 8;
      uint4 v = *(const uint4*)(epi + rrow * 72 + colb);
      const int rr = m0 + wm + rrow;
      const int bb = rr >> 10, tt = rr & 1023;
      *(uint4*)(h1p + (size_t)(bb * TPAD + tt + 2) * C2 + n0 + wn + colb) = v;
    }
  } else {
    float* fepi = (float*)(smem + wave * 4608);   // 2 x (16 x 68) f32
    float* outf = (float*)outv;
#pragma unroll
    for (int mi = 0; mi < 4; mi++) {
      float* fp = fepi + (mi & 1) * 1088;
#pragma unroll
      for (int ni = 0; ni < 4; ni++)
#pragma unroll
        for (int r = 0; r < 4; r++)
          fp[(quad * 4 + r) * 68 + ni * 16 + l16] = acc[mi][ni][r] + bv[ni];
#pragma unroll
      for (int p = 0; p < 4; p++) {
        const int rrow = p * 4 + (lane >> 4);
        const int col  = (lane & 15) * 4;
        float4 v = *(const float4*)(fp + rrow * 68 + col);
        *(float4*)(outf + (size_t)(m0 + wm + mi * 16 + rrow) * CC + n0 + wn + col) = v;
      }
    }
  }
}

// ---------------------------------------------------------------------------
// 5-tap conv: 256M x 128N block, 4 waves in 2x2 of 128M x 64N wave tiles.
// A: row-major stride-40, SINGLE-buffered rows 0..259, 5-reg relay (1-chunk
//    distance, proven R13), stored at chunk top.
// B: staged by global_load_lds DIRECT into linear frag-major LDS: tile
//    (tap, g) = 1024B at lsB + (tap*8+g)*1024; wave w issues g=w and g=w+4
//    for all 5 taps (10 issues); per-lane global src
//    w2t[tap*C2 + n0 + g*16 + (l&15)][kb + (l>>4)*8]; reads lane-linear
//    (lane*16B) -> both sides conflict-free, no swizzle, no relay regs.
// 2 barriers/chunk. barrier2's auto vmcnt(0) lands the B gloads (L2-hot,
// ~200cy, covered by A ds_writes in between).  61.8 KB LDS -> 2 blocks/CU.
// acc[8][4] = 128 AGPR; arch ~90 -> ~218 total, real margin (R14 spilled
// at 256).
__global__ __launch_bounds__(256, 2) void conv5_mfma(
    const u16* __restrict__ h1p, const u16* __restrict__ w2t,
    const float* __restrict__ b2, u16* __restrict__ out) {
  __shared__ __align__(16) u16 smem[30880];  // lsA 10400 | lsB 20480 @10400
  const int tid = threadIdx.x;
  const int mt  = blockIdx.x;                // m-tile 0..63 (256 rows each)
  const int n0  = blockIdx.y * 128;          // n-tile 0..7
  const int bb  = mt >> 2;
  const int t0  = (mt & 3) * 256;
  const size_t arow0 = (size_t)bb * TPAD + t0;
  const int wave = tid >> 6, lane = tid & 63;
  const int wm = (wave & 1) * 128, wn = (wave >> 1) * 64;
  const int quad = lane >> 4, l16 = lane & 15;
  const int row = tid >> 2;            // 0..63
  const int kc  = (tid & 3) * 8;       // 0/8/16/24
  u16* lsB = smem + 10400;

  const u16* Ap0 = h1p + (arow0 + row) * C2 + kc;
  const u16* Ap1 = Ap0 + (size_t)64 * C2;
  const u16* Ap2 = Ap0 + (size_t)128 * C2;
  const u16* Ap3 = Ap0 + (size_t)192 * C2;
  const u16* Ap4 = h1p + (arow0 + 256 + row) * C2 + kc;   // tid<16: rows 256..259

  // per-lane B global bases: g = wave (Bb0) and g = wave+4 (Bb1)
  const u16* Bb0 = w2t + (size_t)(n0 + wave * 16 + (lane & 15)) * C2 + (lane >> 4) * 8;
  const u16* Bb1 = Bb0 + (size_t)64 * C2;

  f32x4 acc[8][4] = {};
  uint4 rA0, rA1, rA2, rA3, rA4;

  // B gload: tap t, g-slot (wave or wave+4), chunk elem offset I0.
#define BG(PTR, T5, GQ, I0)                                                    \
  __builtin_amdgcn_global_load_lds(                                            \
      (glb_u16*)((PTR) + (size_t)(T5) * C2 * C2 + (I0)),                       \
      (lds_u16*)(lsB + ((T5) * 8 + (GQ)) * 512), 16, 0, 0);

  // prologue: A(0) -> regs only (stored at top of chunk 0)
  rA0 = *(const uint4*)Ap0; rA1 = *(const uint4*)Ap1;
  rA2 = *(const uint4*)Ap2; rA3 = *(const uint4*)Ap3;
  if (tid < 16) rA4 = *(const uint4*)Ap4;

#pragma unroll 1
  for (int j = 0; j < 32; j++) {
    __syncthreads();                       // chunk j-1 LDS reads complete
    {                                      // issue B(j) gloads first (latency)
      const int ib0 = j * 32;
#pragma unroll
      for (int t5 = 0; t5 < 5; t5++) {
        BG(Bb0, t5, wave, ib0)
        BG(Bb1, t5, wave + 4, ib0)
      }
    }
    *(uint4*)(smem + row * 40 + kc)         = rA0;   // lsA = A(j)
    *(uint4*)(smem + (64 + row) * 40 + kc)  = rA1;
    *(uint4*)(smem + (128 + row) * 40 + kc) = rA2;
    *(uint4*)(smem + (192 + row) * 40 + kc) = rA3;
    if (tid < 16) *(uint4*)(smem + (256 + row) * 40 + kc) = rA4;
    __syncthreads();                       // vmcnt(0)+lgkmcnt(0): staging visible
    {                                      // relay A(j+1)
      const int ia = (j + 1 < 32) ? (j + 1) * 32 : 0;
      rA0 = *(const uint4*)(Ap0 + ia);
      rA1 = *(const uint4*)(Ap1 + ia);
      rA2 = *(const uint4*)(Ap2 + ia);
      rA3 = *(const uint4*)(Ap3 + ia);
      if (tid < 16) rA4 = *(const uint4*)(Ap4 + ia);
    }
#pragma unroll
    for (int k = 0; k < 5; k++) {
      bf16x8 bfr[4];
#pragma unroll
      for (int i = 0; i < 4; i++)
        bfr[i] = *(const bf16x8*)(lsB + (k * 8 + (wn >> 4) + i) * 512 + lane * 8);
#pragma unroll
      for (int h = 0; h < 2; h++) {
        bf16x8 af[4];
#pragma unroll
        for (int i = 0; i < 4; i++)
          af[i] = *(const bf16x8*)(smem + (wm + (h * 4 + i) * 16 + l16 + k) * 40 + quad * 8);
#pragma unroll
        for (int mi = 0; mi < 4; mi++)
#pragma unroll
          for (int ni = 0; ni < 4; ni++)
            acc[h * 4 + mi][ni] = __builtin_amdgcn_mfma_f32_16x16x32_bf16(
                af[mi], bfr[ni], acc[h * 4 + mi][ni], 0, 0, 0);
      }
    }
  }
#undef BG
  __syncthreads();

  float bv[4];
#pragma unroll
  for (int ni = 0; ni < 4; ni++) bv[ni] = b2[n0 + wn + ni * 16 + l16];

  u16* epi = smem + wave * 4608;         // 64 x 72 u16, private per wave
  const size_t orow0 = (size_t)bb * TT + t0;
#pragma unroll
  for (int h = 0; h < 2; h++) {
#pragma unroll
    for (int mi = 0; mi < 4; mi++)
#pragma unroll
      for (int ni = 0; ni < 4; ni++)
#pragma unroll
        for (int r = 0; r < 4; r++)
          epi[(mi * 16 + quad * 4 + r) * 72 + ni * 16 + l16] =
              f2bf(acc[h * 4 + mi][ni][r] + bv[ni]);
#pragma unroll
    for (int p = 0; p < 8; p++) {
      const int rrow = p * 8 + (lane >> 3);
      const int colb = (lane & 7) * 8;
      uint4 v = *(const uint4*)(epi + rrow * 72 + colb);
      *(uint4*)(out + (orow0 + wm + h * 64 + rrow) * C2 + n0 + wn + colb) = v;
    }
  }
}

// ---------------------------------------------------------------------------
__global__ __launch_bounds__(256) void glu_bn_k(
    const u16* __restrict__ hc, const float* __restrict__ bg,
    const float* __restrict__ bb_, const float* __restrict__ bm,
    const float* __restrict__ bv, u16* __restrict__ out) {
  const int idx = blockIdx.x * 256 + threadIdx.x;
  const int r  = idx >> 6;
  const int c8 = (idx & 63) * 8;
  const u16* pa = hc + (size_t)r * C2 + c8;
  uint4 ra = *(const uint4*)pa;
  uint4 rg = *(const uint4*)(pa + CC);
  u16 av[8], gv[8], ov[8];
  *(uint4*)av = ra; *(uint4*)gv = rg;
#pragma unroll
  for (int j = 0; j < 8; j++) {
    const int c = c8 + j;
    const float a = bf2f(av[j]);
    const float g = bf2f(gv[j]);
    const float h = a / (1.f + __expf(-g));
    const float sc = bg[c] * rsqrtf(bv[c] + 1e-5f);
    ov[j] = f2bf((h - bm[c]) * sc + bb_[c]);
  }
  *(uint4*)(out + (size_t)r * CC + c8) = *(const uint4*)ov;
}

// ---------------------------------------------------------------------------
extern "C" void kernel_launch(void* const* d_in, const int* in_sizes, int n_in,
                              void* d_out, int out_size, void* d_ws, size_t ws_size,
                              hipStream_t stream) {
  const float* x   = (const float*)d_in[0];
  const float* lng = (const float*)d_in[1];
  const float* lnb = (const float*)d_in[2];
  const float* w1  = (const float*)d_in[3];
  const float* b1  = (const float*)d_in[4];
  const float* w2  = (const float*)d_in[5];
  const float* b2  = (const float*)d_in[6];
  const float* bng = (const float*)d_in[7];
  const float* bnb = (const float*)d_in[8];
  const float* bnm = (const float*)d_in[9];
  const float* bnv = (const float*)d_in[10];
  const float* w3  = (const float*)d_in[11];
  const float* b3  = (const float*)d_in[12];

  u16* ws  = (u16*)d_ws;
  u16* hln = ws;                               // 16384*512
  u16* h2  = hln;                              // alias (hln dead after GEMM1)
  u16* h1p = ws + 8388608;                     // 16*1028*1024
  u16* w2t = h1p + 16842752;                   // 5*1024*1024
  u16* hcv = w2t + 5242880;                    // 16384*1024
  u16* w1b = hcv + 16777216;                   // 1024*512
  u16* w3b = w1b + 524288;                     // 512*512

  prep_k      <<<800, 256, 0, stream>>>(w1, w1b, w3, w3b, h1p);
  transpose_w2<<<dim3(16, 16, 5), dim3(64, 4), 0, stream>>>(w2, w2t);
  layernorm_k <<<4096, 256, 0, stream>>>(x, lng, lnb, hln);
  gemm_bt<0>  <<<dim3(128, 8), 256, 0, stream>>>(hln, w1b, b1, h1p, 512, 512);
  conv5_mfma  <<<dim3(64, 8), 256, 0, stream>>>(h1p, w2t, b2, hcv);
  glu_bn_k    <<<4096, 256, 0, stream>>>(hcv, bng, bnb, bnm, bnv, h2);
  gemm_bt<1>  <<<dim3(128, 4), 256, 0, stream>>>(h2, w3b, b3, d_out, 512, 512);
}

// Round 7
// 310.259 us; speedup vs baseline: 1.1533x; 1.0353x over previous
//
#include <hip/hip_runtime.h>
#include <cstdint>

// ---------------------------------------------------------------------------
// ConvModule: LN -> GEMM(512->1024)+SiLU -> conv K=5 (1024->1024) -> GLU ->
//             BN -> GEMM(512->512).  B=16, T=1024, C=512. fp32 I/O, bf16 MFMA.
// Round 16: GLU+BN fused into conv epilogue. Conv block y now computes
// PAIRED cols {y*64..+63} U {512+y*64..+63} (a-half + g-half): only the two
// B gload base pointers change; main loop/LDS/MFMA byte-identical to R15.
// Waves 0/1 hold a, waves 2/3 hold g for the same m rows; epilogue does a
// 2-half LDS exchange (stride-72, proven pattern), h=a*sigmoid(g), BN,
// writes h2 (16MB) directly. hcv (32MB W + 32MB R) and glu_bn_k eliminated.
// Numerics bit-identical (old path also bf16-roundtripped a,g via hcv).
// R15 base: 256Mx128N tile, 128x64 wave tiles, B via global_load_lds direct
// (no relay regs/swizzle), A 5-reg relay 1-chunk, 61.8KB LDS, VGPR 124.
// Lessons: indexed reg arrays spill (R5/R8); named scalars don't (R9);
// direct-global frags TCP-bound (R4/R6/R7); never exceed (VGPR+AGPR)=256
// at 2-wave (R14); occupancy not the conv limiter (R13).
// ---------------------------------------------------------------------------

#define NB    16
#define TT    1024
#define CC    512
#define C2    1024
#define TPAD  1028        // T + 4 pad rows (2 each side) per batch

typedef unsigned short u16;
typedef short bf16x8 __attribute__((ext_vector_type(8)));
typedef float f32x4  __attribute__((ext_vector_type(4)));
typedef __attribute__((address_space(3))) u16 lds_u16;
typedef const __attribute__((address_space(1))) u16 glb_u16;

__device__ __forceinline__ float bf2f(u16 u) {
  union { unsigned int i; float f; } v; v.i = ((unsigned int)u) << 16; return v.f;
}
__device__ __forceinline__ u16 f2bf(float f) {
  union { float f; unsigned int i; } v; v.f = f;
  unsigned int x = v.i;
  return (u16)((x + 0x7fffu + ((x >> 16) & 1u)) >> 16);  // RNE
}

// ---------------------------------------------------------------------------
__global__ __launch_bounds__(256) void prep_k(
    const float* __restrict__ w1, u16* __restrict__ w1b,
    const float* __restrict__ w3, u16* __restrict__ w3b,
    u16* __restrict__ h1p) {
  const int b = blockIdx.x;
  if (b < 512) {
    const int i = (b * 256 + threadIdx.x) * 4;
    float4 v = *(const float4*)(w1 + i);
    u16 o[4] = { f2bf(v.x), f2bf(v.y), f2bf(v.z), f2bf(v.w) };
    *(uint2*)(w1b + i) = *(const uint2*)o;
  } else if (b < 768) {
    const int i = ((b - 512) * 256 + threadIdx.x) * 4;
    float4 v = *(const float4*)(w3 + i);
    u16 o[4] = { f2bf(v.x), f2bf(v.y), f2bf(v.z), f2bf(v.w) };
    *(uint2*)(w3b + i) = *(const uint2*)o;
  } else {
    const int idx = (b - 768) * 256 + threadIdx.x;
    const int bb  = idx >> 9;
    const int rem = idx & 511;
    const int ri  = rem >> 7;
    const int c8  = (rem & 127) * 8;
    const int row = bb * TPAD + (ri < 2 ? ri : 1024 + ri);   // 0,1,1026,1027
    uint4 z = make_uint4(0u, 0u, 0u, 0u);
    *(uint4*)(h1p + (size_t)row * C2 + c8) = z;
  }
}

// ---------------------------------------------------------------------------
// w2 fp32 (K, I, O) -> w2t bf16 (K, O, I)
__global__ void transpose_w2(const float* __restrict__ w2, u16* __restrict__ w2t) {
  __shared__ u16 t[64][65];
  const int k  = blockIdx.z;
  const int i0 = blockIdx.x * 64, o0 = blockIdx.y * 64;
  const int tx = threadIdx.x, ty = threadIdx.y;
  for (int r = ty; r < 64; r += 4)
    t[r][tx] = f2bf(w2[((size_t)(k * C2) + i0 + r) * C2 + o0 + tx]);
  __syncthreads();
  for (int r = ty; r < 64; r += 4)
    w2t[((size_t)(k * C2) + o0 + r) * C2 + i0 + tx] = t[tx][r];
}

// ---------------------------------------------------------------------------
__global__ __launch_bounds__(256) void layernorm_k(
    const float* __restrict__ x, const float* __restrict__ lng,
    const float* __restrict__ lnb, u16* __restrict__ out) {
  const int tok  = blockIdx.x * 4 + (threadIdx.x >> 6);
  const int lane = threadIdx.x & 63;
  const float* xp = x + (size_t)tok * CC + lane * 8;
  float f[8];
  *(float4*)(f)     = *(const float4*)(xp);
  *(float4*)(f + 4) = *(const float4*)(xp + 4);
  float s = 0.f, s2 = 0.f;
#pragma unroll
  for (int j = 0; j < 8; j++) { s += f[j]; s2 += f[j] * f[j]; }
#pragma unroll
  for (int m = 32; m >= 1; m >>= 1) { s += __shfl_xor(s, m, 64); s2 += __shfl_xor(s2, m, 64); }
  const float mu  = s  * (1.f / 512.f);
  const float var = s2 * (1.f / 512.f) - mu * mu;
  const float rs  = rsqrtf(var + 1e-5f);
  u16 ov[8];
#pragma unroll
  for (int j = 0; j < 8; j++) {
    const int c = lane * 8 + j;
    ov[j] = f2bf((f[j] - mu) * rs * lng[c] + lnb[c]);
  }
  *(uint4*)(out + (size_t)tok * CC + lane * 8) = *(const uint4*)ov;
}

// ---------------------------------------------------------------------------
// GEMM out[m,n] = sum_k A[m,k]*Bt[n,k] + bias[n].  128x128 tile, BK=32.
// (R8/R9 version — proven, kept.)
template <int EPI>
__global__ __launch_bounds__(256, 3) void gemm_bt(
    const u16* __restrict__ A, const u16* __restrict__ Bt,
    const float* __restrict__ bias, void* __restrict__ outv,
    const int Kd, const int ldA) {
  __shared__ __align__(16) u16 smem[20480];   // lsA 2x5120 | lsB 2x5120
  const int tid  = threadIdx.x;
  const int m0   = blockIdx.x * 128;
  const int n0   = blockIdx.y * 128;
  const int wave = tid >> 6, lane = tid & 63;
  const int wm = (wave & 1) * 64, wn = (wave >> 1) * 64;
  const int quad = lane >> 4, l16 = lane & 15;
  const int row = tid >> 2;            // 0..63
  const int kc  = (tid & 3) * 8;       // 0/8/16/24
  const int J = Kd >> 5;               // 16

  const u16* Ap0 = A + (size_t)(m0 + row) * ldA + kc;
  const u16* Ap1 = Ap0 + (size_t)64 * ldA;
  const u16* Bp0 = Bt + (size_t)(n0 + row) * Kd + kc;
  const u16* Bp1 = Bp0 + (size_t)64 * Kd;

  f32x4 acc[4][4] = {};
  uint4 rA0 = *(const uint4*)Ap0, rA1 = *(const uint4*)Ap1;
  uint4 rB0 = *(const uint4*)Bp0, rB1 = *(const uint4*)Bp1;
  *(uint4*)(smem + row * 40 + kc)                = rA0;
  *(uint4*)(smem + (64 + row) * 40 + kc)         = rA1;
  *(uint4*)(smem + 10240 + row * 40 + kc)        = rB0;
  *(uint4*)(smem + 10240 + (64 + row) * 40 + kc) = rB1;
  rA0 = *(const uint4*)(Ap0 + 32); rA1 = *(const uint4*)(Ap1 + 32);
  rB0 = *(const uint4*)(Bp0 + 32); rB1 = *(const uint4*)(Bp1 + 32);
  __syncthreads();

#pragma unroll 1
  for (int j = 0; j < J; j++) {
    const u16* curA = smem + (j & 1) * 5120;
    const u16* curB = smem + 10240 + (j & 1) * 5120;
    if (j + 1 < J) {
      u16* nxtA = smem + ((j + 1) & 1) * 5120;
      u16* nxtB = smem + 10240 + ((j + 1) & 1) * 5120;
      *(uint4*)(nxtA + row * 40 + kc)        = rA0;
      *(uint4*)(nxtA + (64 + row) * 40 + kc) = rA1;
      *(uint4*)(nxtB + row * 40 + kc)        = rB0;
      *(uint4*)(nxtB + (64 + row) * 40 + kc) = rB1;
    }
    {
      const int k2 = (j + 2 < J) ? (j + 2) * 32 : 0;
      rA0 = *(const uint4*)(Ap0 + k2); rA1 = *(const uint4*)(Ap1 + k2);
      rB0 = *(const uint4*)(Bp0 + k2); rB1 = *(const uint4*)(Bp1 + k2);
    }
    bf16x8 af[4], bfr[4];
#pragma unroll
    for (int i = 0; i < 4; i++)
      af[i] = *(const bf16x8*)(curA + (wm + i * 16 + l16) * 40 + quad * 8);
#pragma unroll
    for (int i = 0; i < 4; i++)
      bfr[i] = *(const bf16x8*)(curB + (wn + i * 16 + l16) * 40 + quad * 8);
#pragma unroll
    for (int mi = 0; mi < 4; mi++)
#pragma unroll
      for (int ni = 0; ni < 4; ni++)
        acc[mi][ni] = __builtin_amdgcn_mfma_f32_16x16x32_bf16(
            af[mi], bfr[ni], acc[mi][ni], 0, 0, 0);
    __syncthreads();
  }

  float bv[4];
#pragma unroll
  for (int ni = 0; ni < 4; ni++) bv[ni] = bias[n0 + wn + ni * 16 + l16];

  if (EPI == 0) {
    u16* epi = smem + wave * 4608;       // 64 x 72 u16, private
#pragma unroll
    for (int mi = 0; mi < 4; mi++)
#pragma unroll
      for (int ni = 0; ni < 4; ni++)
#pragma unroll
        for (int r = 0; r < 4; r++) {
          float v = acc[mi][ni][r] + bv[ni];
          v = v / (1.f + __expf(-v));    // SiLU
          epi[(mi * 16 + quad * 4 + r) * 72 + ni * 16 + l16] = f2bf(v);
        }
    u16* h1p = (u16*)outv;
#pragma unroll
    for (int p = 0; p < 8; p++) {
      const int rrow = p * 8 + (lane >> 3);
      const int colb = (lane & 7) * 8;
      uint4 v = *(const uint4*)(epi + rrow * 72 + colb);
      const int rr = m0 + wm + rrow;
      const int bb = rr >> 10, tt = rr & 1023;
      *(uint4*)(h1p + (size_t)(bb * TPAD + tt + 2) * C2 + n0 + wn + colb) = v;
    }
  } else {
    float* fepi = (float*)(smem + wave * 4608);   // 2 x (16 x 68) f32
    float* outf = (float*)outv;
#pragma unroll
    for (int mi = 0; mi < 4; mi++) {
      float* fp = fepi + (mi & 1) * 1088;
#pragma unroll
      for (int ni = 0; ni < 4; ni++)
#pragma unroll
        for (int r = 0; r < 4; r++)
          fp[(quad * 4 + r) * 68 + ni * 16 + l16] = acc[mi][ni][r] + bv[ni];
#pragma unroll
      for (int p = 0; p < 4; p++) {
        const int rrow = p * 4 + (lane >> 4);
        const int col  = (lane & 15) * 4;
        float4 v = *(const float4*)(fp + rrow * 68 + col);
        *(float4*)(outf + (size_t)(m0 + wm + mi * 16 + rrow) * CC + n0 + wn + col) = v;
      }
    }
  }
}

// ---------------------------------------------------------------------------
// 5-tap conv + fused GLU/BN: 256M rows x paired-128N cols per block.
// Block y computes a-cols [y*64, y*64+64) and g-cols [512+y*64, +64).
// Waves 0/1 (wn=0) -> a (B slots 0..3 <- Bb0), waves 2/3 (wn=64) -> g
// (slots 4..7 <- Bb1).  Main loop identical to R15 (only gload bases
// differ).  Epilogue: 2 m-halves; a-wave + g-wave write bf16 acc+bias to
// stride-72 LDS bufs (proven pattern), then all waves compute
// h = a*sigmoid(g), BN, store h2 (16384x512 bf16) coalesced.
// hcv + glu_bn_k eliminated (saves 64MB HBM + a launch).
__global__ __launch_bounds__(256, 2) void conv5_mfma(
    const u16* __restrict__ h1p, const u16* __restrict__ w2t,
    const float* __restrict__ b2,
    const float* __restrict__ bng, const float* __restrict__ bnb,
    const float* __restrict__ bnm, const float* __restrict__ bnv,
    u16* __restrict__ h2) {
  __shared__ __align__(16) u16 smem[30880];  // lsA 10400 | lsB 20480 @10400
  const int tid = threadIdx.x;
  const int mt  = blockIdx.x;                // m-tile 0..63 (256 rows each)
  const int ya  = blockIdx.y * 64;           // a-col base; g-col base 512+ya
  const int bb  = mt >> 2;
  const int t0  = (mt & 3) * 256;
  const size_t arow0 = (size_t)bb * TPAD + t0;
  const int wave = tid >> 6, lane = tid & 63;
  const int wm = (wave & 1) * 128, wn = (wave >> 1) * 64;
  const int quad = lane >> 4, l16 = lane & 15;
  const int row = tid >> 2;            // 0..63
  const int kc  = (tid & 3) * 8;       // 0/8/16/24
  u16* lsB = smem + 10400;

  const u16* Ap0 = h1p + (arow0 + row) * C2 + kc;
  const u16* Ap1 = Ap0 + (size_t)64 * C2;
  const u16* Ap2 = Ap0 + (size_t)128 * C2;
  const u16* Ap3 = Ap0 + (size_t)192 * C2;
  const u16* Ap4 = h1p + (arow0 + 256 + row) * C2 + kc;   // tid<16: rows 256..259

  // per-lane B global bases: slot g=wave (a-half), slot g=wave+4 (g-half)
  const u16* Bb0 = w2t + (size_t)(ya + wave * 16 + (lane & 15)) * C2 + (lane >> 4) * 8;
  const u16* Bb1 = w2t + (size_t)(512 + ya + wave * 16 + (lane & 15)) * C2 + (lane >> 4) * 8;

  f32x4 acc[8][4] = {};
  uint4 rA0, rA1, rA2, rA3, rA4;

  // B gload: tap t, g-slot (wave or wave+4), chunk elem offset I0.
#define BG(PTR, T5, GQ, I0)                                                    \
  __builtin_amdgcn_global_load_lds(                                            \
      (glb_u16*)((PTR) + (size_t)(T5) * C2 * C2 + (I0)),                       \
      (lds_u16*)(lsB + ((T5) * 8 + (GQ)) * 512), 16, 0, 0);

  // prologue: A(0) -> regs only (stored at top of chunk 0)
  rA0 = *(const uint4*)Ap0; rA1 = *(const uint4*)Ap1;
  rA2 = *(const uint4*)Ap2; rA3 = *(const uint4*)Ap3;
  if (tid < 16) rA4 = *(const uint4*)Ap4;

#pragma unroll 1
  for (int j = 0; j < 32; j++) {
    __syncthreads();                       // chunk j-1 LDS reads complete
    {                                      // issue B(j) gloads first (latency)
      const int ib0 = j * 32;
#pragma unroll
      for (int t5 = 0; t5 < 5; t5++) {
        BG(Bb0, t5, wave, ib0)
        BG(Bb1, t5, wave + 4, ib0)
      }
    }
    *(uint4*)(smem + row * 40 + kc)         = rA0;   // lsA = A(j)
    *(uint4*)(smem + (64 + row) * 40 + kc)  = rA1;
    *(uint4*)(smem + (128 + row) * 40 + kc) = rA2;
    *(uint4*)(smem + (192 + row) * 40 + kc) = rA3;
    if (tid < 16) *(uint4*)(smem + (256 + row) * 40 + kc) = rA4;
    __syncthreads();                       // vmcnt(0)+lgkmcnt(0): staging visible
    {                                      // relay A(j+1)
      const int ia = (j + 1 < 32) ? (j + 1) * 32 : 0;
      rA0 = *(const uint4*)(Ap0 + ia);
      rA1 = *(const uint4*)(Ap1 + ia);
      rA2 = *(const uint4*)(Ap2 + ia);
      rA3 = *(const uint4*)(Ap3 + ia);
      if (tid < 16) rA4 = *(const uint4*)(Ap4 + ia);
    }
#pragma unroll
    for (int k = 0; k < 5; k++) {
      bf16x8 bfr[4];
#pragma unroll
      for (int i = 0; i < 4; i++)
        bfr[i] = *(const bf16x8*)(lsB + (k * 8 + (wn >> 4) + i) * 512 + lane * 8);
#pragma unroll
      for (int h = 0; h < 2; h++) {
        bf16x8 af[4];
#pragma unroll
        for (int i = 0; i < 4; i++)
          af[i] = *(const bf16x8*)(smem + (wm + (h * 4 + i) * 16 + l16 + k) * 40 + quad * 8);
#pragma unroll
        for (int mi = 0; mi < 4; mi++)
#pragma unroll
          for (int ni = 0; ni < 4; ni++)
            acc[h * 4 + mi][ni] = __builtin_amdgcn_mfma_f32_16x16x32_bf16(
                af[mi], bfr[ni], acc[h * 4 + mi][ni], 0, 0, 0);
      }
    }
  }
#undef BG
  __syncthreads();

  // bias for this wave's cols: waves 0/1 -> a (b2 col ya+..), 2/3 -> g (512+ya+..)
  float bv[4];
#pragma unroll
  for (int ni = 0; ni < 4; ni++)
    bv[ni] = b2[(wn >> 6) * 512 + ya + ni * 16 + l16];

  // BN params for final store cols (per-lane 8 cols, same every row)
  const int cb8 = (lane & 7) * 8;
  float sc8[8], bm8[8], bb8[8];
#pragma unroll
  for (int jj = 0; jj < 8; jj++) {
    const int c = ya + cb8 + jj;
    sc8[jj] = bng[c] * rsqrtf(bnv[c] + 1e-5f);
    bm8[jj] = bnm[c];
    bb8[jj] = bnb[c];
  }

  u16* abuf = smem;          // 128 x 72
  u16* gbuf = smem + 9216;   // 128 x 72
  const size_t orow0 = (size_t)bb * TT + t0;
#pragma unroll 1
  for (int hh = 0; hh < 2; hh++) {
    if ((wave & 1) == hh) {            // this wave's m-rows are this half
      u16* buf = (wn >> 6) ? gbuf : abuf;
#pragma unroll
      for (int mi = 0; mi < 8; mi++)
#pragma unroll
        for (int ni = 0; ni < 4; ni++)
#pragma unroll
          for (int r = 0; r < 4; r++)
            buf[(mi * 16 + quad * 4 + r) * 72 + ni * 16 + l16] =
                f2bf(acc[mi][ni][r] + bv[ni]);
    }
    __syncthreads();
#pragma unroll
    for (int p = 0; p < 4; p++) {
      const int rr = wave * 32 + p * 8 + (lane >> 3);
      uint4 va = *(const uint4*)(abuf + rr * 72 + cb8);
      uint4 vg = *(const uint4*)(gbuf + rr * 72 + cb8);
      u16 aa[8], gg[8], oo[8];
      *(uint4*)aa = va; *(uint4*)gg = vg;
#pragma unroll
      for (int jj = 0; jj < 8; jj++) {
        const float a = bf2f(aa[jj]);
        const float g = bf2f(gg[jj]);
        const float h = a / (1.f + __expf(-g));
        oo[jj] = f2bf((h - bm8[jj]) * sc8[jj] + bb8[jj]);
      }
      *(uint4*)(h2 + (orow0 + hh * 128 + rr) * CC + ya + cb8) = *(const uint4*)oo;
    }
    __syncthreads();
  }
}

// ---------------------------------------------------------------------------
extern "C" void kernel_launch(void* const* d_in, const int* in_sizes, int n_in,
                              void* d_out, int out_size, void* d_ws, size_t ws_size,
                              hipStream_t stream) {
  const float* x   = (const float*)d_in[0];
  const float* lng = (const float*)d_in[1];
  const float* lnb = (const float*)d_in[2];
  const float* w1  = (const float*)d_in[3];
  const float* b1  = (const float*)d_in[4];
  const float* w2  = (const float*)d_in[5];
  const float* b2  = (const float*)d_in[6];
  const float* bng = (const float*)d_in[7];
  const float* bnb = (const float*)d_in[8];
  const float* bnm = (const float*)d_in[9];
  const float* bnv = (const float*)d_in[10];
  const float* w3  = (const float*)d_in[11];
  const float* b3  = (const float*)d_in[12];

  u16* ws  = (u16*)d_ws;
  u16* hln = ws;                               // 16384*512
  u16* h2  = hln;                              // alias (hln dead after GEMM1)
  u16* h1p = ws + 8388608;                     // 16*1028*1024
  u16* w2t = h1p + 16842752;                   // 5*1024*1024
  u16* hcv = w2t + 5242880;                    // (unused after R16 fusion)
  u16* w1b = hcv + 16777216;                   // 1024*512
  u16* w3b = w1b + 524288;                     // 512*512

  prep_k      <<<800, 256, 0, stream>>>(w1, w1b, w3, w3b, h1p);
  transpose_w2<<<dim3(16, 16, 5), dim3(64, 4), 0, stream>>>(w2, w2t);
  layernorm_k <<<4096, 256, 0, stream>>>(x, lng, lnb, hln);
  gemm_bt<0>  <<<dim3(128, 8), 256, 0, stream>>>(hln, w1b, b1, h1p, 512, 512);
  conv5_mfma  <<<dim3(64, 8), 256, 0, stream>>>(h1p, w2t, b2, bng, bnb, bnm, bnv, h2);
  gemm_bt<1>  <<<dim3(128, 4), 256, 0, stream>>>(h2, w3b, b3, d_out, 512, 512);
}